// Round 1
// baseline (446.577 us; speedup 1.0000x reference)
//
#include <hip/hip_runtime.h>
#include <stdint.h>

#define BATCH 32
#define CIN   128
#define HH    56
#define WW    56
#define COUT  256
#define HP    58
#define WP    58

typedef __attribute__((ext_vector_type(8))) short short8;
typedef __attribute__((ext_vector_type(4))) float floatx4;

__device__ __forceinline__ unsigned short f32_to_bf16(float f) {
  unsigned int u = __float_as_uint(f);
  u = u + 0x7fffu + ((u >> 16) & 1u);
  return (unsigned short)(u >> 16);
}

// ws layout: [xp_t: BATCH*HP*WP*CIN bf16][slack 1024][wt: 9*COUT*CIN bf16]
// xp_t is NHWC padded: xp_t[((b*58 + i)*58 + j)*128 + ci] = x[b][ci][i-1][j-1] or 0.
// A-tile reads may overrun a row by up to (63+2-57) cols; those land in later
// rows / the 1024-elem slack and only feed discarded output rows (w>=56).

__global__ void pad_transpose_kernel(const float* __restrict__ x,
                                     unsigned short* __restrict__ xpt) {
  __shared__ float tile[CIN * 59];  // stride 59: gcd(59,32)=1 -> 2-way = free
  const int blk = blockIdx.x;       // b*58 + i
  const int b = blk / HP;
  const int i = blk - b * HP;
  const int t = threadIdx.x;
  for (int e = t; e < CIN * 59; e += 256) tile[e] = 0.0f;
  __syncthreads();
  if (i >= 1 && i <= HH) {
    for (int e = t; e < CIN * WW; e += 256) {
      int ci = e / WW;
      int w = e - ci * WW;
      tile[ci * 59 + w + 1] =
          x[(((size_t)b * CIN + ci) * HH + (i - 1)) * WW + w];
    }
  }
  __syncthreads();
  unsigned short* dst = xpt + (size_t)blk * (WP * CIN);
  for (int e = t; e < WP * CIN; e += 256) {
    int j = e >> 7;        // col 0..57
    int ci = e & 127;
    dst[e] = f32_to_bf16(tile[ci * 59 + j]);
  }
}

// wt[r][co][ci] = weight[co][ci][r], bf16.  Total 9*256*128 = 294912 elems.
__global__ void weight_transpose_kernel(const float* __restrict__ wsrc,
                                        unsigned short* __restrict__ wt) {
  int o = blockIdx.x * 256 + threadIdx.x;
  int ci = o & 127;
  int co = (o >> 7) & 255;
  int r = o >> 15;
  wt[o] = f32_to_bf16(wsrc[((size_t)co * CIN + ci) * 9 + r]);
}

// 128x128 block tile, BK=32, 4 waves (2x2), 64x64 per wave = 4x4 mfma tiles.
// M-tile = (b, h-pair): mm 0..127 -> h' = h0 + (mm>>6), w = mm&63 (w>=56 discarded).
__global__ __launch_bounds__(256) void conv_gemm_kernel(
    const unsigned short* __restrict__ xpt,
    const unsigned short* __restrict__ wt,
    const float* __restrict__ bias,
    float* __restrict__ out) {
  __shared__ short As[128 * 40];  // [mm][k], stride 40 shorts = 80 B
  __shared__ short Bs[128 * 40];  // [n][k]

  const int nt = blockIdx.x & 1;
  const int mt = blockIdx.x >> 1;  // 0..895
  const int b = mt / 28;
  const int h0 = (mt - b * 28) * 2;
  const int co0 = nt * 128;

  const int t = threadIdx.x;
  const int lane = t & 63;
  const int wv = t >> 6;
  const int mw = wv & 1;
  const int nw = wv >> 1;
  const int laneM = lane & 15;
  const int laneK = (lane >> 4) * 8;

  floatx4 acc[4][4] = {};

  for (int r = 0; r < 9; ++r) {
    const int dh = r / 3;
    const int dw = r - dh * 3;
#pragma unroll
    for (int kt = 0; kt < 4; ++kt) {
      const int ci0 = kt * 32;
      uint4 aval[2], bval[2];
#pragma unroll
      for (int c = 0; c < 2; ++c) {
        const int u = t + c * 256;       // 0..511
        const int mm = u >> 2;           // 0..127
        const int j8 = (u & 3) * 8;
        const int hprime = h0 + (mm >> 6) + dh;          // <= 57, in range
        const int wcol = (mm & 63) + dw;                 // may overrun: ok
        const size_t ga =
            ((size_t)((b * HP + hprime) * WP + wcol)) * CIN + ci0 + j8;
        aval[c] = *(const uint4*)(xpt + ga);
        const size_t gb = (size_t)r * (COUT * CIN) +
                          (size_t)(co0 + mm) * CIN + ci0 + j8;
        bval[c] = *(const uint4*)(wt + gb);
      }
      __syncthreads();  // previous iteration's frag reads done
#pragma unroll
      for (int c = 0; c < 2; ++c) {
        const int u = t + c * 256;
        const int mm = u >> 2;
        const int j8 = (u & 3) * 8;
        *(uint4*)&As[mm * 40 + j8] = aval[c];
        *(uint4*)&Bs[mm * 40 + j8] = bval[c];
      }
      __syncthreads();
      short8 af[4], bfr[4];
#pragma unroll
      for (int mi = 0; mi < 4; ++mi)
        af[mi] = *(const short8*)&As[(mw * 64 + mi * 16 + laneM) * 40 + laneK];
#pragma unroll
      for (int ni = 0; ni < 4; ++ni)
        bfr[ni] = *(const short8*)&Bs[(nw * 64 + ni * 16 + laneM) * 40 + laneK];
#pragma unroll
      for (int mi = 0; mi < 4; ++mi)
#pragma unroll
        for (int ni = 0; ni < 4; ++ni)
          acc[mi][ni] = __builtin_amdgcn_mfma_f32_16x16x32_bf16(
              af[mi], bfr[ni], acc[mi][ni], 0, 0, 0);
    }
  }

  // Epilogue: D col = lane&15 (co), row = (lane>>4)*4 + reg (w, 4 consecutive).
  const int rowreg = (lane >> 4) * 4;
  const int hout = h0 + mw;
#pragma unroll
  for (int mi = 0; mi < 4; ++mi) {
    const int w0 = mi * 16 + rowreg;
    if (w0 < WW) {
#pragma unroll
      for (int ni = 0; ni < 4; ++ni) {
        const int co = co0 + nw * 64 + ni * 16 + laneM;
        const float bv = bias[co];
        floatx4 v = acc[mi][ni];
        float4 o;
        o.x = v[0] + bv;
        o.y = v[1] + bv;
        o.z = v[2] + bv;
        o.w = v[3] + bv;
        *(float4*)(out + (((size_t)b * COUT + co) * HH + hout) * WW + w0) = o;
      }
    }
  }
}

// Fallback if ws is too small for the bf16 workspace: correct but slow.
__global__ void naive_conv_kernel(const float* __restrict__ x,
                                  const float* __restrict__ wgt,
                                  const float* __restrict__ bias,
                                  float* __restrict__ out, long n) {
  long idx = (long)blockIdx.x * 256 + threadIdx.x;
  if (idx >= n) return;
  int w = (int)(idx % WW);
  long q = idx / WW;
  int h = (int)(q % HH);
  q /= HH;
  int co = (int)(q % COUT);
  int b = (int)(q / COUT);
  float s = bias[co];
  for (int ci = 0; ci < CIN; ++ci) {
    const float* xp = x + (((size_t)b * CIN + ci) * HH) * WW;
    const float* wp = wgt + ((size_t)co * CIN + ci) * 9;
    for (int dh = 0; dh < 3; ++dh) {
      int hh = h + dh - 1;
      if (hh < 0 || hh >= HH) continue;
      for (int dw = 0; dw < 3; ++dw) {
        int ww2 = w + dw - 1;
        if (ww2 < 0 || ww2 >= WW) continue;
        s += xp[hh * WW + ww2] * wp[dh * 3 + dw];
      }
    }
  }
  out[idx] = s;
}

extern "C" void kernel_launch(void* const* d_in, const int* in_sizes, int n_in,
                              void* d_out, int out_size, void* d_ws,
                              size_t ws_size, hipStream_t stream) {
  const float* x = (const float*)d_in[0];
  const float* wgt = (const float*)d_in[1];
  const float* bias = (const float*)d_in[2];
  float* out = (float*)d_out;

  const size_t XPT = (size_t)BATCH * HP * WP * CIN;  // 13,778,944
  const size_t SLACK = 1024;
  const size_t WT = (size_t)9 * COUT * CIN;  // 294,912
  const size_t need = (XPT + SLACK + WT) * sizeof(unsigned short);

  if (ws_size >= need) {
    unsigned short* xpt = (unsigned short*)d_ws;
    unsigned short* wtp = xpt + XPT + SLACK;
    hipLaunchKernelGGL(pad_transpose_kernel, dim3(BATCH * HP), dim3(256), 0,
                       stream, x, xpt);
    hipLaunchKernelGGL(weight_transpose_kernel, dim3((9 * COUT * CIN) / 256),
                       dim3(256), 0, stream, wgt, wtp);
    hipLaunchKernelGGL(conv_gemm_kernel, dim3(896 * 2), dim3(256), 0, stream,
                       xpt, wtp, bias, out);
  } else {
    long n = (long)out_size;
    hipLaunchKernelGGL(naive_conv_kernel, dim3((unsigned)((n + 255) / 256)),
                       dim3(256), 0, stream, x, wgt, bias, out, n);
  }
}